// Round 1
// baseline (1135.402 us; speedup 1.0000x reference)
//
#include <hip/hip_runtime.h>

// ---------------------------------------------------------------------------
// GAT (5 layers, 8 heads / last 1 head) + final linear, fp32 throughout.
// Strategy: build dst-CSR once per call (reused by all 5 layers), then per
// layer: tiled fp32 GEMM (h = x@W), attention-logit kernel (al_s/al_d),
// per-node wave softmax+aggregate kernel (no atomics in hot path).
// ---------------------------------------------------------------------------

__global__ __launch_bounds__(256) void k_deg_init(int* deg, int n) {
  int i = blockIdx.x * 256 + threadIdx.x;
  if (i < n) deg[i] = 1;  // self loop
}

__global__ __launch_bounds__(256) void k_count(const int* __restrict__ ei, int E, int* deg) {
  int i = blockIdx.x * 256 + threadIdx.x;
  if (i < E) atomicAdd(&deg[ei[E + i]], 1);
}

// single-block exclusive scan of deg[0..n) -> row_ptr[0..n], also fills cursor
__global__ __launch_bounds__(1024) void k_scan(const int* __restrict__ deg,
                                               int* __restrict__ row_ptr,
                                               int* __restrict__ cursor, int n) {
  __shared__ int part[1024];
  int t = threadIdx.x;
  int chunk = (n + 1023) >> 10;
  int lo = t * chunk; if (lo > n) lo = n;
  int hi = lo + chunk; if (hi > n) hi = n;
  int s = 0;
  for (int i = lo; i < hi; i++) s += deg[i];
  part[t] = s;
  __syncthreads();
  for (int off = 1; off < 1024; off <<= 1) {
    int v = (t >= off) ? part[t - off] : 0;
    __syncthreads();
    part[t] += v;
    __syncthreads();
  }
  int run = part[t] - s;  // exclusive prefix of this thread's chunk
  for (int i = lo; i < hi; i++) { row_ptr[i] = run; cursor[i] = run; run += deg[i]; }
  if (hi == n) row_ptr[n] = run;
}

__global__ __launch_bounds__(256) void k_fill(const int* __restrict__ ei, int E, int n,
                                              int* cursor, int* __restrict__ srcs) {
  int i = blockIdx.x * 256 + threadIdx.x;
  if (i >= E + n) return;
  int s, d;
  if (i < E) { s = ei[i]; d = ei[E + i]; }
  else       { s = i - E; d = s; }        // self loops
  int slot = atomicAdd(&cursor[d], 1);
  srcs[slot] = s;
}

// ---------------------------------------------------------------------------
// C[M,128] = A[M,128] @ W[128,128] (+bias, +relu). fp32, register-tiled.
// block = 256 threads, tile 64 rows x 128 cols, per-thread 4x8 accumulator.
// ---------------------------------------------------------------------------
__global__ __launch_bounds__(256) void k_gemm(const float* __restrict__ A,
                                              const float* __restrict__ W,
                                              const float* __restrict__ bias,
                                              float* __restrict__ C, int M, int relu) {
  __shared__ float As[32][65];    // As[k][m], +1 pad -> conflict-light stores/reads
  __shared__ float Bs[32][128];
  int tid = threadIdx.x;
  int row0 = blockIdx.x * 64;
  int tx = tid & 15;   // col group: cols tx*8 .. +7
  int ty = tid >> 4;   // row group: rows ty*4 .. +3
  float acc[4][8] = {};
  for (int kt = 0; kt < 128; kt += 32) {
    #pragma unroll
    for (int i = 0; i < 2; i++) {         // A tile: 64x32 floats
      int idx = tid + i * 256;
      int r = idx >> 3;
      int k4 = (idx & 7) << 2;
      float4 v = make_float4(0.f, 0.f, 0.f, 0.f);
      int gr = row0 + r;
      if (gr < M) v = *(const float4*)(A + (size_t)gr * 128 + kt + k4);
      As[k4 + 0][r] = v.x; As[k4 + 1][r] = v.y; As[k4 + 2][r] = v.z; As[k4 + 3][r] = v.w;
    }
    #pragma unroll
    for (int i = 0; i < 4; i++) {         // W tile: 32x128 floats
      int idx = tid + i * 256;
      int k = idx >> 5;
      int n4 = (idx & 31) << 2;
      *(float4*)(&Bs[k][n4]) = *(const float4*)(W + (size_t)(kt + k) * 128 + n4);
    }
    __syncthreads();
    #pragma unroll
    for (int k = 0; k < 32; k++) {
      float a0 = As[k][ty * 4 + 0], a1 = As[k][ty * 4 + 1];
      float a2 = As[k][ty * 4 + 2], a3 = As[k][ty * 4 + 3];
      float b[8];
      *(float4*)&b[0] = *(const float4*)&Bs[k][tx * 8];
      *(float4*)&b[4] = *(const float4*)&Bs[k][tx * 8 + 4];
      #pragma unroll
      for (int j = 0; j < 8; j++) {
        acc[0][j] += a0 * b[j];
        acc[1][j] += a1 * b[j];
        acc[2][j] += a2 * b[j];
        acc[3][j] += a3 * b[j];
      }
    }
    __syncthreads();
  }
  #pragma unroll
  for (int i = 0; i < 4; i++) {
    int r = row0 + ty * 4 + i;
    if (r >= M) continue;
    #pragma unroll
    for (int j4 = 0; j4 < 8; j4 += 4) {
      int c = tx * 8 + j4;
      float4 v;
      v.x = acc[i][j4 + 0]; v.y = acc[i][j4 + 1];
      v.z = acc[i][j4 + 2]; v.w = acc[i][j4 + 3];
      if (bias) { v.x += bias[c]; v.y += bias[c + 1]; v.z += bias[c + 2]; v.w += bias[c + 3]; }
      if (relu) {
        v.x = fmaxf(v.x, 0.f); v.y = fmaxf(v.y, 0.f);
        v.z = fmaxf(v.z, 0.f); v.w = fmaxf(v.w, 0.f);
      }
      *(float4*)(C + (size_t)r * 128 + c) = v;
    }
  }
}

// al_s/al_d for H=8 (C=16): one thread per (node, head), float4 loads.
__global__ __launch_bounds__(256) void k_al8(const float* __restrict__ h,
                                             const float* __restrict__ a_s,
                                             const float* __restrict__ a_d,
                                             float* __restrict__ als, float* __restrict__ ald, int n) {
  int g = blockIdx.x * 256 + threadIdx.x;
  if (g >= n * 8) return;
  int hd = g & 7;
  const float4* hp = (const float4*)(h + (size_t)g * 16);
  const float4* ap = (const float4*)(a_s + hd * 16);
  const float4* dp = (const float4*)(a_d + hd * 16);
  float ss = 0.f, sd = 0.f;
  #pragma unroll
  for (int i = 0; i < 4; i++) {
    float4 hv = hp[i], av = ap[i], dv = dp[i];
    ss += hv.x * av.x + hv.y * av.y + hv.z * av.z + hv.w * av.w;
    sd += hv.x * dv.x + hv.y * dv.y + hv.z * dv.z + hv.w * dv.w;
  }
  als[g] = ss; ald[g] = sd;
}

// al_s/al_d for H=1 (C=128): 16 lanes per node + shfl reduce.
__global__ __launch_bounds__(256) void k_al1(const float* __restrict__ h,
                                             const float* __restrict__ a_s,
                                             const float* __restrict__ a_d,
                                             float* __restrict__ als, float* __restrict__ ald, int n) {
  int g = blockIdx.x * 256 + threadIdx.x;
  int v = g >> 4, q = g & 15;
  bool act = (v < n);
  float ss = 0.f, sd = 0.f;
  if (act) {
    float4 hv = *(const float4*)(h + (size_t)v * 128 + q * 4);
    float4 av = *(const float4*)(a_s + q * 4);
    float4 dv = *(const float4*)(a_d + q * 4);
    ss = hv.x * av.x + hv.y * av.y + hv.z * av.z + hv.w * av.w;
    sd = hv.x * dv.x + hv.y * dv.y + hv.z * dv.z + hv.w * dv.w;
  }
  #pragma unroll
  for (int off = 1; off < 16; off <<= 1) { ss += __shfl_xor(ss, off); sd += __shfl_xor(sd, off); }
  if (act && q == 0) { als[v] = ss; ald[v] = sd; }
}

// ---------------------------------------------------------------------------
// Per-node softmax + aggregation. One wave (64 lanes) per destination node.
// Phase 1: e = leakyrelu(al_s[src]+al_d[v]) per (edge,head), per-head max.
// Phase 2: p = exp(e-max), per-head denom. p stored to global scratch (CSR slot).
// Phase 3: each lane owns 2 output channels; loop edges, acc += alpha*h[src].
// ---------------------------------------------------------------------------
template <int H>
__global__ __launch_bounds__(256) void k_agg(const int* __restrict__ row_ptr,
                                             const int* __restrict__ srcs,
                                             const float* __restrict__ als,
                                             const float* __restrict__ ald,
                                             const float* __restrict__ h,
                                             const float* __restrict__ bias,
                                             float* __restrict__ scr,
                                             float* __restrict__ out, int n) {
  const int C = 128 / H;
  const int EPP = 64 / H;  // edges per wave-pass
  int lane = threadIdx.x & 63;
  int wv = threadIdx.x >> 6;
  int v = blockIdx.x * 4 + wv;
  bool active = (v < n);
  int s0 = 0, s1 = 0;
  int eo = lane / H;       // edge offset within pass
  int hd = lane % H;       // head for phases 1-2
  float ed = 0.f;
  if (active) {
    s0 = row_ptr[v]; s1 = row_ptr[v + 1];
    ed = ald[v * H + hd];
  }
  // phase 1: logits + per-head max
  float m = -1e30f;
  for (int j = s0 + eo; j < s1; j += EPP) {
    int sv = srcs[j];
    float e = als[sv * H + hd] + ed;
    e = (e > 0.f) ? e : 0.2f * e;
    m = fmaxf(m, e);
    scr[(size_t)j * H + hd] = e;
  }
  #pragma unroll
  for (int off = H; off < 64; off <<= 1) m = fmaxf(m, __shfl_xor(m, off));
  // phase 2: exp + per-head denom
  float denom = 0.f;
  for (int j = s0 + eo; j < s1; j += EPP) {
    float p = __expf(scr[(size_t)j * H + hd] - m);
    scr[(size_t)j * H + hd] = p;
    denom += p;
  }
  #pragma unroll
  for (int off = H; off < 64; off <<= 1) denom += __shfl_xor(denom, off);
  float inv = (denom > 0.f) ? 1.f / denom : 0.f;
  __syncthreads();  // make scr stores visible across lanes/waves (block scope)
  // phase 3: weighted aggregation; lane owns channels c0, c0+1
  int c0 = lane * 2;
  int hd3 = c0 / C;
  float invb = __shfl(inv, hd3);  // lane hd3 holds head hd3's denom (hd3 % H == hd3)
  float acc0 = 0.f, acc1 = 0.f;
  for (int j = s0; j < s1; j++) {
    int sv = srcs[j];
    float al = scr[(size_t)j * H + hd3] * invb;
    float2 hv = *(const float2*)(h + (size_t)sv * 128 + c0);
    acc0 += al * hv.x;
    acc1 += al * hv.y;
  }
  if (active) {
    acc0 += bias[c0]; acc1 += bias[c0 + 1];
    out[(size_t)v * 128 + c0]     = fmaxf(acc0, 0.f);
    out[(size_t)v * 128 + c0 + 1] = fmaxf(acc1, 0.f);
  }
}

extern "C" void kernel_launch(void* const* d_in, const int* in_sizes, int n_in,
                              void* d_out, int out_size, void* d_ws, size_t ws_size,
                              hipStream_t stream) {
  const float* x  = (const float*)d_in[0];
  const int*   ei = (const int*)d_in[1];
  // d_in[2] = edge_attr (unused by reference)
  const int N  = in_sizes[0] / 128;
  const int E  = in_sizes[1] / 2;
  const int ET = E + N;

  const float *Wl[5], *as[5], *ad[5], *bl[5];
  for (int l = 0; l < 5; l++) {
    Wl[l] = (const float*)d_in[3 + 4 * l];
    as[l] = (const float*)d_in[4 + 4 * l];
    ad[l] = (const float*)d_in[5 + 4 * l];
    bl[l] = (const float*)d_in[6 + 4 * l];
  }
  const float* W_lin = (const float*)d_in[23];
  const float* b_lin = (const float*)d_in[24];

  char* p = (char*)d_ws;
  auto alloc = [&](size_t bytes) { void* r = (void*)p; p += (bytes + 255) & ~size_t(255); return r; };
  float* h    = (float*)alloc((size_t)N * 128 * 4);
  float* xA   = (float*)alloc((size_t)N * 128 * 4);
  float* xB   = (float*)alloc((size_t)N * 128 * 4);
  float* als  = (float*)alloc((size_t)N * 8 * 4);
  float* ald  = (float*)alloc((size_t)N * 8 * 4);
  float* scr  = (float*)alloc((size_t)ET * 8 * 4);
  int* row_ptr = (int*)alloc((size_t)(N + 1) * 4);
  int* cursor  = (int*)alloc((size_t)N * 4);
  int* deg     = (int*)alloc((size_t)N * 4);
  int* srcs    = (int*)alloc((size_t)ET * 4);
  (void)ws_size; (void)n_in; (void)out_size;

  dim3 b256(256);
  // CSR build (once; reused across all 5 layers)
  k_deg_init<<<(N + 255) / 256, b256, 0, stream>>>(deg, N);
  k_count<<<(E + 255) / 256, b256, 0, stream>>>(ei, E, deg);
  k_scan<<<1, 1024, 0, stream>>>(deg, row_ptr, cursor, N);
  k_fill<<<(ET + 255) / 256, b256, 0, stream>>>(ei, E, N, cursor, srcs);

  int gemm_grid = (N + 63) / 64;
  const float* xin = x;
  float* bufs[2] = { xA, xB };
  for (int l = 0; l < 5; l++) {
    float* xout = bufs[l & 1];
    k_gemm<<<gemm_grid, b256, 0, stream>>>(xin, Wl[l], nullptr, h, N, 0);
    if (l < 4) {
      k_al8<<<(N * 8 + 255) / 256, b256, 0, stream>>>(h, as[l], ad[l], als, ald, N);
      k_agg<8><<<(N + 3) / 4, b256, 0, stream>>>(row_ptr, srcs, als, ald, h, bl[l], scr, xout, N);
    } else {
      k_al1<<<(N * 16 + 255) / 256, b256, 0, stream>>>(h, as[l], ad[l], als, ald, N);
      k_agg<1><<<(N + 3) / 4, b256, 0, stream>>>(row_ptr, srcs, als, ald, h, bl[l], scr, xout, N);
    }
    xin = xout;
  }
  k_gemm<<<gemm_grid, b256, 0, stream>>>(xin, W_lin, b_lin, (float*)d_out, N, 1);
}

// Round 2
// 908.110 us; speedup vs baseline: 1.2503x; 1.2503x over previous
//
#include <hip/hip_runtime.h>

// ---------------------------------------------------------------------------
// GAT (5 layers, 8 heads / last 1 head) + final linear, fp32 throughout.
// dst-CSR built once per call; per layer: tiled fp32 GEMM, attention logits,
// fused online-softmax + aggregation (one wave per destination node, no
// scratch round-trip, no atomics in the hot path).
// ---------------------------------------------------------------------------

__global__ __launch_bounds__(256) void k_deg_init(int* deg, int n) {
  int i = blockIdx.x * 256 + threadIdx.x;
  if (i < n) deg[i] = 1;  // self loop
}

__global__ __launch_bounds__(256) void k_count(const int* __restrict__ ei, int E, int* deg) {
  int i = blockIdx.x * 256 + threadIdx.x;
  if (i < E) atomicAdd(&deg[ei[E + i]], 1);
}

// single-block exclusive scan of deg[0..n) -> row_ptr[0..n], also fills cursor
__global__ __launch_bounds__(1024) void k_scan(const int* __restrict__ deg,
                                               int* __restrict__ row_ptr,
                                               int* __restrict__ cursor, int n) {
  __shared__ int part[1024];
  int t = threadIdx.x;
  int chunk = (n + 1023) >> 10;
  int lo = t * chunk; if (lo > n) lo = n;
  int hi = lo + chunk; if (hi > n) hi = n;
  int s = 0;
  for (int i = lo; i < hi; i++) s += deg[i];
  part[t] = s;
  __syncthreads();
  for (int off = 1; off < 1024; off <<= 1) {
    int v = (t >= off) ? part[t - off] : 0;
    __syncthreads();
    part[t] += v;
    __syncthreads();
  }
  int run = part[t] - s;  // exclusive prefix of this thread's chunk
  for (int i = lo; i < hi; i++) { row_ptr[i] = run; cursor[i] = run; run += deg[i]; }
  if (hi == n) row_ptr[n] = run;
}

__global__ __launch_bounds__(256) void k_fill(const int* __restrict__ ei, int E, int n,
                                              int* cursor, int* __restrict__ srcs) {
  int i = blockIdx.x * 256 + threadIdx.x;
  if (i >= E + n) return;
  int s, d;
  if (i < E) { s = ei[i]; d = ei[E + i]; }
  else       { s = i - E; d = s; }        // self loops
  int slot = atomicAdd(&cursor[d], 1);
  srcs[slot] = s;
}

// ---------------------------------------------------------------------------
// C[M,128] = A[M,128] @ W[128,128] (+bias, +relu). fp32, register-tiled.
// block = 256 threads, tile 64 rows x 128 cols, per-thread 4x8 accumulator.
// ---------------------------------------------------------------------------
__global__ __launch_bounds__(256) void k_gemm(const float* __restrict__ A,
                                              const float* __restrict__ W,
                                              const float* __restrict__ bias,
                                              float* __restrict__ C, int M, int relu) {
  __shared__ float As[32][65];    // As[k][m], +1 pad -> conflict-light stores/reads
  __shared__ float Bs[32][128];
  int tid = threadIdx.x;
  int row0 = blockIdx.x * 64;
  int tx = tid & 15;   // col group: cols tx*8 .. +7
  int ty = tid >> 4;   // row group: rows ty*4 .. +3
  float acc[4][8] = {};
  for (int kt = 0; kt < 128; kt += 32) {
    #pragma unroll
    for (int i = 0; i < 2; i++) {         // A tile: 64x32 floats
      int idx = tid + i * 256;
      int r = idx >> 3;
      int k4 = (idx & 7) << 2;
      float4 v = make_float4(0.f, 0.f, 0.f, 0.f);
      int gr = row0 + r;
      if (gr < M) v = *(const float4*)(A + (size_t)gr * 128 + kt + k4);
      As[k4 + 0][r] = v.x; As[k4 + 1][r] = v.y; As[k4 + 2][r] = v.z; As[k4 + 3][r] = v.w;
    }
    #pragma unroll
    for (int i = 0; i < 4; i++) {         // W tile: 32x128 floats
      int idx = tid + i * 256;
      int k = idx >> 5;
      int n4 = (idx & 31) << 2;
      *(float4*)(&Bs[k][n4]) = *(const float4*)(W + (size_t)(kt + k) * 128 + n4);
    }
    __syncthreads();
    #pragma unroll
    for (int k = 0; k < 32; k++) {
      float a0 = As[k][ty * 4 + 0], a1 = As[k][ty * 4 + 1];
      float a2 = As[k][ty * 4 + 2], a3 = As[k][ty * 4 + 3];
      float b[8];
      *(float4*)&b[0] = *(const float4*)&Bs[k][tx * 8];
      *(float4*)&b[4] = *(const float4*)&Bs[k][tx * 8 + 4];
      #pragma unroll
      for (int j = 0; j < 8; j++) {
        acc[0][j] += a0 * b[j];
        acc[1][j] += a1 * b[j];
        acc[2][j] += a2 * b[j];
        acc[3][j] += a3 * b[j];
      }
    }
    __syncthreads();
  }
  #pragma unroll
  for (int i = 0; i < 4; i++) {
    int r = row0 + ty * 4 + i;
    if (r >= M) continue;
    #pragma unroll
    for (int j4 = 0; j4 < 8; j4 += 4) {
      int c = tx * 8 + j4;
      float4 v;
      v.x = acc[i][j4 + 0]; v.y = acc[i][j4 + 1];
      v.z = acc[i][j4 + 2]; v.w = acc[i][j4 + 3];
      if (bias) { v.x += bias[c]; v.y += bias[c + 1]; v.z += bias[c + 2]; v.w += bias[c + 3]; }
      if (relu) {
        v.x = fmaxf(v.x, 0.f); v.y = fmaxf(v.y, 0.f);
        v.z = fmaxf(v.z, 0.f); v.w = fmaxf(v.w, 0.f);
      }
      *(float4*)(C + (size_t)r * 128 + c) = v;
    }
  }
}

// al_s/al_d for H=8 (C=16): one thread per (node, head), float4 loads.
__global__ __launch_bounds__(256) void k_al8(const float* __restrict__ h,
                                             const float* __restrict__ a_s,
                                             const float* __restrict__ a_d,
                                             float* __restrict__ als, float* __restrict__ ald, int n) {
  int g = blockIdx.x * 256 + threadIdx.x;
  if (g >= n * 8) return;
  int hd = g & 7;
  const float4* hp = (const float4*)(h + (size_t)g * 16);
  const float4* ap = (const float4*)(a_s + hd * 16);
  const float4* dp = (const float4*)(a_d + hd * 16);
  float ss = 0.f, sd = 0.f;
  #pragma unroll
  for (int i = 0; i < 4; i++) {
    float4 hv = hp[i], av = ap[i], dv = dp[i];
    ss += hv.x * av.x + hv.y * av.y + hv.z * av.z + hv.w * av.w;
    sd += hv.x * dv.x + hv.y * dv.y + hv.z * dv.z + hv.w * dv.w;
  }
  als[g] = ss; ald[g] = sd;
}

// al_s/al_d for H=1 (C=128): 16 lanes per node + shfl reduce.
__global__ __launch_bounds__(256) void k_al1(const float* __restrict__ h,
                                             const float* __restrict__ a_s,
                                             const float* __restrict__ a_d,
                                             float* __restrict__ als, float* __restrict__ ald, int n) {
  int g = blockIdx.x * 256 + threadIdx.x;
  int v = g >> 4, q = g & 15;
  bool act = (v < n);
  float ss = 0.f, sd = 0.f;
  if (act) {
    float4 hv = *(const float4*)(h + (size_t)v * 128 + q * 4);
    float4 av = *(const float4*)(a_s + q * 4);
    float4 dv = *(const float4*)(a_d + q * 4);
    ss = hv.x * av.x + hv.y * av.y + hv.z * av.z + hv.w * av.w;
    sd = hv.x * dv.x + hv.y * dv.y + hv.z * dv.z + hv.w * dv.w;
  }
  #pragma unroll
  for (int off = 1; off < 16; off <<= 1) { ss += __shfl_xor(ss, off); sd += __shfl_xor(sd, off); }
  if (act && q == 0) { als[v] = ss; ald[v] = sd; }
}

// ---------------------------------------------------------------------------
// Fused per-node online-softmax + aggregation. One wave per destination node.
// Pass 1: lane (eo,hd) walks edges eo, eo+EPP, ... computing running (max,
//         denom) online; cross-lane merge over eo via shfl_xor -> per-head
//         (m, d) in every lane with hd == head.
// Pass 2: 32 lanes x float4 channels, 2 edge slots (lane>>5); alpha
//         recomputed inline from als (L2-hot, 1.6 MB); slot-merge via
//         shfl_xor(32); lanes 0..31 store float4.
// No scratch buffer, no barrier, waves fully independent.
// ---------------------------------------------------------------------------
template <int H>
__global__ __launch_bounds__(256) void k_agg(const int* __restrict__ row_ptr,
                                             const int* __restrict__ srcs,
                                             const float* __restrict__ als,
                                             const float* __restrict__ ald,
                                             const float* __restrict__ h,
                                             const float* __restrict__ bias,
                                             float* __restrict__ out, int n) {
  const int EPP = 64 / H;  // edges per wave-pass in pass 1
  int lane = threadIdx.x & 63;
  int wv = threadIdx.x >> 6;
  int v = blockIdx.x * 4 + wv;
  bool active = (v < n);
  int s0 = 0, s1 = 0;
  int eo = lane / H;       // edge offset within pass
  int hd = lane % H;       // head for pass 1
  float ed = 0.f;
  if (active) { s0 = row_ptr[v]; s1 = row_ptr[v + 1]; ed = ald[v * H + hd]; }
  // pass 1: online softmax (m, d)
  float m = -1e30f, d = 0.f;
  for (int j = s0 + eo; j < s1; j += EPP) {
    int sv = srcs[j];
    float e = als[sv * H + hd] + ed;
    e = (e > 0.f) ? e : 0.2f * e;
    float nm = fmaxf(m, e);
    d = d * __expf(m - nm) + __expf(e - nm);
    m = nm;
  }
  #pragma unroll
  for (int off = H; off < 64; off <<= 1) {
    float om = __shfl_xor(m, off);
    float od = __shfl_xor(d, off);
    float nm = fmaxf(m, om);
    d = d * __expf(m - nm) + od * __expf(om - nm);
    m = nm;
  }
  // pass 2: aggregation. lane = slot*32 + l5; channels c0..c0+3.
  int slot = lane >> 5;
  int l5 = lane & 31;
  int c0 = l5 * 4;
  int hd3 = (H == 1) ? 0 : (c0 / (128 / H));   // head owning channel c0
  float m3 = __shfl(m, hd3);                   // lane hd3 holds head hd3 (hd3%H==hd3)
  float inv = 1.f / __shfl(d, hd3);            // d >= 1 (self loop) -> safe
  float ed3 = __shfl(ed, hd3);
  float ax = 0.f, ay = 0.f, az = 0.f, aw = 0.f;
  #pragma unroll 2
  for (int j = s0 + slot; j < s1; j += 2) {
    int sv = srcs[j];
    float e = als[sv * H + hd3] + ed3;
    e = (e > 0.f) ? e : 0.2f * e;
    float al = __expf(e - m3) * inv;
    float4 hv = *(const float4*)(h + (size_t)sv * 128 + c0);
    ax += al * hv.x; ay += al * hv.y; az += al * hv.z; aw += al * hv.w;
  }
  ax += __shfl_xor(ax, 32);
  ay += __shfl_xor(ay, 32);
  az += __shfl_xor(az, 32);
  aw += __shfl_xor(aw, 32);
  if (active && slot == 0) {
    float4 o;
    o.x = fmaxf(ax + bias[c0 + 0], 0.f);
    o.y = fmaxf(ay + bias[c0 + 1], 0.f);
    o.z = fmaxf(az + bias[c0 + 2], 0.f);
    o.w = fmaxf(aw + bias[c0 + 3], 0.f);
    *(float4*)(out + (size_t)v * 128 + c0) = o;
  }
}

extern "C" void kernel_launch(void* const* d_in, const int* in_sizes, int n_in,
                              void* d_out, int out_size, void* d_ws, size_t ws_size,
                              hipStream_t stream) {
  const float* x  = (const float*)d_in[0];
  const int*   ei = (const int*)d_in[1];
  // d_in[2] = edge_attr (unused by reference)
  const int N  = in_sizes[0] / 128;
  const int E  = in_sizes[1] / 2;
  const int ET = E + N;

  const float *Wl[5], *as[5], *ad[5], *bl[5];
  for (int l = 0; l < 5; l++) {
    Wl[l] = (const float*)d_in[3 + 4 * l];
    as[l] = (const float*)d_in[4 + 4 * l];
    ad[l] = (const float*)d_in[5 + 4 * l];
    bl[l] = (const float*)d_in[6 + 4 * l];
  }
  const float* W_lin = (const float*)d_in[23];
  const float* b_lin = (const float*)d_in[24];

  char* p = (char*)d_ws;
  auto alloc = [&](size_t bytes) { void* r = (void*)p; p += (bytes + 255) & ~size_t(255); return r; };
  float* h    = (float*)alloc((size_t)N * 128 * 4);
  float* xA   = (float*)alloc((size_t)N * 128 * 4);
  float* xB   = (float*)alloc((size_t)N * 128 * 4);
  float* als  = (float*)alloc((size_t)N * 8 * 4);
  float* ald  = (float*)alloc((size_t)N * 8 * 4);
  int* row_ptr = (int*)alloc((size_t)(N + 1) * 4);
  int* cursor  = (int*)alloc((size_t)N * 4);
  int* deg     = (int*)alloc((size_t)N * 4);
  int* srcs    = (int*)alloc((size_t)ET * 4);
  (void)ws_size; (void)n_in; (void)out_size;

  dim3 b256(256);
  // CSR build (once; reused across all 5 layers)
  k_deg_init<<<(N + 255) / 256, b256, 0, stream>>>(deg, N);
  k_count<<<(E + 255) / 256, b256, 0, stream>>>(ei, E, deg);
  k_scan<<<1, 1024, 0, stream>>>(deg, row_ptr, cursor, N);
  k_fill<<<(ET + 255) / 256, b256, 0, stream>>>(ei, E, N, cursor, srcs);

  int gemm_grid = (N + 63) / 64;
  const float* xin = x;
  float* bufs[2] = { xA, xB };
  for (int l = 0; l < 5; l++) {
    float* xout = bufs[l & 1];
    k_gemm<<<gemm_grid, b256, 0, stream>>>(xin, Wl[l], nullptr, h, N, 0);
    if (l < 4) {
      k_al8<<<(N * 8 + 255) / 256, b256, 0, stream>>>(h, as[l], ad[l], als, ald, N);
      k_agg<8><<<(N + 3) / 4, b256, 0, stream>>>(row_ptr, srcs, als, ald, h, bl[l], xout, N);
    } else {
      k_al1<<<(N * 16 + 255) / 256, b256, 0, stream>>>(h, as[l], ad[l], als, ald, N);
      k_agg<1><<<(N + 3) / 4, b256, 0, stream>>>(row_ptr, srcs, als, ald, h, bl[l], xout, N);
    }
    xin = xout;
  }
  k_gemm<<<gemm_grid, b256, 0, stream>>>(xin, W_lin, b_lin, (float*)d_out, N, 1);
}

// Round 3
// 797.663 us; speedup vs baseline: 1.4234x; 1.1385x over previous
//
#include <hip/hip_runtime.h>

// ---------------------------------------------------------------------------
// GAT (5 layers, 8 heads / last 1 head) + final linear, fp32 throughout.
// dst-CSR built once per call (hierarchical 3-kernel scan); per layer:
// tiled fp32 GEMM, attention logits, fused online-softmax + aggregation
// (one wave per destination node, no scratch round-trip, no atomics in the
// hot path).
// ---------------------------------------------------------------------------

__global__ __launch_bounds__(256) void k_deg_init(int* deg, int n) {
  int i = blockIdx.x * 256 + threadIdx.x;
  if (i < n) deg[i] = 1;  // self loop
}

__global__ __launch_bounds__(256) void k_count(const int* __restrict__ ei, int E, int* deg) {
  int i = blockIdx.x * 256 + threadIdx.x;
  if (i < E) atomicAdd(&deg[ei[E + i]], 1);
}

// 256-thread block exclusive scan helper. Returns exclusive prefix of v;
// *tot (if non-null) gets the block total. Uses wave shfl_up + LDS.
__device__ __forceinline__ int block_excl_scan(int v, int* tot) {
  __shared__ int wsum[4];
  int lane = threadIdx.x & 63, w = threadIdx.x >> 6;
  int x = v;
  #pragma unroll
  for (int off = 1; off < 64; off <<= 1) {
    int y = __shfl_up(x, off);
    if (lane >= off) x += y;
  }
  if (lane == 63) wsum[w] = x;
  __syncthreads();
  int wbase = 0;
  #pragma unroll
  for (int i = 0; i < 4; i++) wbase += (i < w) ? wsum[i] : 0;
  if (tot) *tot = wsum[0] + wsum[1] + wsum[2] + wsum[3];
  return wbase + x - v;
}

// Phase A: per-block (256-elem) sums of deg -> bsum[b]
__global__ __launch_bounds__(256) void k_bsum(const int* __restrict__ deg, int* __restrict__ bsum, int n) {
  int i = blockIdx.x * 256 + threadIdx.x;
  int v = (i < n) ? deg[i] : 0;
  int tot;
  block_excl_scan(v, &tot);
  if (threadIdx.x == 0) bsum[blockIdx.x] = tot;
}

// Phase B: single small block scans nb (<256) partials -> boff (exclusive)
__global__ __launch_bounds__(256) void k_bscan(const int* __restrict__ bsum, int* __restrict__ boff, int nb) {
  int t = threadIdx.x;
  int v = (t < nb) ? bsum[t] : 0;
  int ex = block_excl_scan(v, nullptr);
  if (t < nb) boff[t] = ex;
}

// Phase C: per-block exclusive scan + block offset -> row_ptr, cursor
__global__ __launch_bounds__(256) void k_rowptr(const int* __restrict__ deg,
                                                const int* __restrict__ boff,
                                                int* __restrict__ row_ptr,
                                                int* __restrict__ cursor, int n) {
  int i = blockIdx.x * 256 + threadIdx.x;
  int v = (i < n) ? deg[i] : 0;
  int ex = block_excl_scan(v, nullptr) + boff[blockIdx.x];
  if (i < n) { row_ptr[i] = ex; cursor[i] = ex; }
  if (i == n - 1) row_ptr[n] = ex + v;  // sentinel
}

__global__ __launch_bounds__(256) void k_fill(const int* __restrict__ ei, int E, int n,
                                              int* cursor, int* __restrict__ srcs) {
  int i = blockIdx.x * 256 + threadIdx.x;
  if (i >= E + n) return;
  int s, d;
  if (i < E) { s = ei[i]; d = ei[E + i]; }
  else       { s = i - E; d = s; }        // self loops
  int slot = atomicAdd(&cursor[d], 1);
  srcs[slot] = s;
}

// ---------------------------------------------------------------------------
// C[M,128] = A[M,128] @ W[128,128] (+bias, +relu). fp32, register-tiled.
// block = 256 threads, tile 64 rows x 128 cols, per-thread 4x8 accumulator.
// ---------------------------------------------------------------------------
__global__ __launch_bounds__(256) void k_gemm(const float* __restrict__ A,
                                              const float* __restrict__ W,
                                              const float* __restrict__ bias,
                                              float* __restrict__ C, int M, int relu) {
  __shared__ float As[32][65];    // As[k][m], +1 pad -> conflict-light stores/reads
  __shared__ float Bs[32][128];
  int tid = threadIdx.x;
  int row0 = blockIdx.x * 64;
  int tx = tid & 15;   // col group: cols tx*8 .. +7
  int ty = tid >> 4;   // row group: rows ty*4 .. +3
  float acc[4][8] = {};
  for (int kt = 0; kt < 128; kt += 32) {
    #pragma unroll
    for (int i = 0; i < 2; i++) {         // A tile: 64x32 floats
      int idx = tid + i * 256;
      int r = idx >> 3;
      int k4 = (idx & 7) << 2;
      float4 v = make_float4(0.f, 0.f, 0.f, 0.f);
      int gr = row0 + r;
      if (gr < M) v = *(const float4*)(A + (size_t)gr * 128 + kt + k4);
      As[k4 + 0][r] = v.x; As[k4 + 1][r] = v.y; As[k4 + 2][r] = v.z; As[k4 + 3][r] = v.w;
    }
    #pragma unroll
    for (int i = 0; i < 4; i++) {         // W tile: 32x128 floats
      int idx = tid + i * 256;
      int k = idx >> 5;
      int n4 = (idx & 31) << 2;
      *(float4*)(&Bs[k][n4]) = *(const float4*)(W + (size_t)(kt + k) * 128 + n4);
    }
    __syncthreads();
    #pragma unroll
    for (int k = 0; k < 32; k++) {
      float a0 = As[k][ty * 4 + 0], a1 = As[k][ty * 4 + 1];
      float a2 = As[k][ty * 4 + 2], a3 = As[k][ty * 4 + 3];
      float b[8];
      *(float4*)&b[0] = *(const float4*)&Bs[k][tx * 8];
      *(float4*)&b[4] = *(const float4*)&Bs[k][tx * 8 + 4];
      #pragma unroll
      for (int j = 0; j < 8; j++) {
        acc[0][j] += a0 * b[j];
        acc[1][j] += a1 * b[j];
        acc[2][j] += a2 * b[j];
        acc[3][j] += a3 * b[j];
      }
    }
    __syncthreads();
  }
  #pragma unroll
  for (int i = 0; i < 4; i++) {
    int r = row0 + ty * 4 + i;
    if (r >= M) continue;
    #pragma unroll
    for (int j4 = 0; j4 < 8; j4 += 4) {
      int c = tx * 8 + j4;
      float4 v;
      v.x = acc[i][j4 + 0]; v.y = acc[i][j4 + 1];
      v.z = acc[i][j4 + 2]; v.w = acc[i][j4 + 3];
      if (bias) { v.x += bias[c]; v.y += bias[c + 1]; v.z += bias[c + 2]; v.w += bias[c + 3]; }
      if (relu) {
        v.x = fmaxf(v.x, 0.f); v.y = fmaxf(v.y, 0.f);
        v.z = fmaxf(v.z, 0.f); v.w = fmaxf(v.w, 0.f);
      }
      *(float4*)(C + (size_t)r * 128 + c) = v;
    }
  }
}

// al_s/al_d for H=8 (C=16): one thread per (node, head), float4 loads.
__global__ __launch_bounds__(256) void k_al8(const float* __restrict__ h,
                                             const float* __restrict__ a_s,
                                             const float* __restrict__ a_d,
                                             float* __restrict__ als, float* __restrict__ ald, int n) {
  int g = blockIdx.x * 256 + threadIdx.x;
  if (g >= n * 8) return;
  int hd = g & 7;
  const float4* hp = (const float4*)(h + (size_t)g * 16);
  const float4* ap = (const float4*)(a_s + hd * 16);
  const float4* dp = (const float4*)(a_d + hd * 16);
  float ss = 0.f, sd = 0.f;
  #pragma unroll
  for (int i = 0; i < 4; i++) {
    float4 hv = hp[i], av = ap[i], dv = dp[i];
    ss += hv.x * av.x + hv.y * av.y + hv.z * av.z + hv.w * av.w;
    sd += hv.x * dv.x + hv.y * dv.y + hv.z * dv.z + hv.w * dv.w;
  }
  als[g] = ss; ald[g] = sd;
}

// al_s/al_d for H=1 (C=128): 16 lanes per node + shfl reduce.
__global__ __launch_bounds__(256) void k_al1(const float* __restrict__ h,
                                             const float* __restrict__ a_s,
                                             const float* __restrict__ a_d,
                                             float* __restrict__ als, float* __restrict__ ald, int n) {
  int g = blockIdx.x * 256 + threadIdx.x;
  int v = g >> 4, q = g & 15;
  bool act = (v < n);
  float ss = 0.f, sd = 0.f;
  if (act) {
    float4 hv = *(const float4*)(h + (size_t)v * 128 + q * 4);
    float4 av = *(const float4*)(a_s + q * 4);
    float4 dv = *(const float4*)(a_d + q * 4);
    ss = hv.x * av.x + hv.y * av.y + hv.z * av.z + hv.w * av.w;
    sd = hv.x * dv.x + hv.y * dv.y + hv.z * dv.z + hv.w * dv.w;
  }
  #pragma unroll
  for (int off = 1; off < 16; off <<= 1) { ss += __shfl_xor(ss, off); sd += __shfl_xor(sd, off); }
  if (act && q == 0) { als[v] = ss; ald[v] = sd; }
}

// ---------------------------------------------------------------------------
// Fused per-node online-softmax + aggregation. One wave per destination node.
// Pass 1: lane (eo,hd) walks edges computing running (max, denom) online;
//         cross-lane merge via shfl_xor -> per-head (m, d).
// Pass 2: 32 lanes x float4 channels, 2 edge slots; alpha recomputed inline
//         from als (L2-hot); slot-merge via shfl_xor(32).
// ---------------------------------------------------------------------------
template <int H>
__global__ __launch_bounds__(256) void k_agg(const int* __restrict__ row_ptr,
                                             const int* __restrict__ srcs,
                                             const float* __restrict__ als,
                                             const float* __restrict__ ald,
                                             const float* __restrict__ h,
                                             const float* __restrict__ bias,
                                             float* __restrict__ out, int n) {
  const int EPP = 64 / H;  // edges per wave-pass in pass 1
  int lane = threadIdx.x & 63;
  int wv = threadIdx.x >> 6;
  int v = blockIdx.x * 4 + wv;
  bool active = (v < n);
  int s0 = 0, s1 = 0;
  int eo = lane / H;       // edge offset within pass
  int hd = lane % H;       // head for pass 1
  float ed = 0.f;
  if (active) { s0 = row_ptr[v]; s1 = row_ptr[v + 1]; ed = ald[v * H + hd]; }
  // pass 1: online softmax (m, d)
  float m = -1e30f, d = 0.f;
  for (int j = s0 + eo; j < s1; j += EPP) {
    int sv = srcs[j];
    float e = als[sv * H + hd] + ed;
    e = (e > 0.f) ? e : 0.2f * e;
    float nm = fmaxf(m, e);
    d = d * __expf(m - nm) + __expf(e - nm);
    m = nm;
  }
  #pragma unroll
  for (int off = H; off < 64; off <<= 1) {
    float om = __shfl_xor(m, off);
    float od = __shfl_xor(d, off);
    float nm = fmaxf(m, om);
    d = d * __expf(m - nm) + od * __expf(om - nm);
    m = nm;
  }
  // pass 2: aggregation. lane = slot*32 + l5; channels c0..c0+3.
  int slot = lane >> 5;
  int l5 = lane & 31;
  int c0 = l5 * 4;
  int hd3 = (H == 1) ? 0 : (c0 / (128 / H));   // head owning channel c0
  float m3 = __shfl(m, hd3);                   // lane hd3 holds head hd3 (hd3%H==hd3)
  float inv = 1.f / __shfl(d, hd3);            // d >= 1 (self loop) -> safe
  float ed3 = __shfl(ed, hd3);
  float ax = 0.f, ay = 0.f, az = 0.f, aw = 0.f;
  #pragma unroll 2
  for (int j = s0 + slot; j < s1; j += 2) {
    int sv = srcs[j];
    float e = als[sv * H + hd3] + ed3;
    e = (e > 0.f) ? e : 0.2f * e;
    float al = __expf(e - m3) * inv;
    float4 hv = *(const float4*)(h + (size_t)sv * 128 + c0);
    ax += al * hv.x; ay += al * hv.y; az += al * hv.z; aw += al * hv.w;
  }
  ax += __shfl_xor(ax, 32);
  ay += __shfl_xor(ay, 32);
  az += __shfl_xor(az, 32);
  aw += __shfl_xor(aw, 32);
  if (active && slot == 0) {
    float4 o;
    o.x = fmaxf(ax + bias[c0 + 0], 0.f);
    o.y = fmaxf(ay + bias[c0 + 1], 0.f);
    o.z = fmaxf(az + bias[c0 + 2], 0.f);
    o.w = fmaxf(aw + bias[c0 + 3], 0.f);
    *(float4*)(out + (size_t)v * 128 + c0) = o;
  }
}

extern "C" void kernel_launch(void* const* d_in, const int* in_sizes, int n_in,
                              void* d_out, int out_size, void* d_ws, size_t ws_size,
                              hipStream_t stream) {
  const float* x  = (const float*)d_in[0];
  const int*   ei = (const int*)d_in[1];
  // d_in[2] = edge_attr (unused by reference)
  const int N  = in_sizes[0] / 128;
  const int E  = in_sizes[1] / 2;
  const int ET = E + N;
  const int NB = (N + 255) / 256;   // scan blocks (196 for N=50000, < 256)

  const float *Wl[5], *as[5], *ad[5], *bl[5];
  for (int l = 0; l < 5; l++) {
    Wl[l] = (const float*)d_in[3 + 4 * l];
    as[l] = (const float*)d_in[4 + 4 * l];
    ad[l] = (const float*)d_in[5 + 4 * l];
    bl[l] = (const float*)d_in[6 + 4 * l];
  }
  const float* W_lin = (const float*)d_in[23];
  const float* b_lin = (const float*)d_in[24];

  char* p = (char*)d_ws;
  auto alloc = [&](size_t bytes) { void* r = (void*)p; p += (bytes + 255) & ~size_t(255); return r; };
  float* h    = (float*)alloc((size_t)N * 128 * 4);
  float* xA   = (float*)alloc((size_t)N * 128 * 4);
  float* xB   = (float*)alloc((size_t)N * 128 * 4);
  float* als  = (float*)alloc((size_t)N * 8 * 4);
  float* ald  = (float*)alloc((size_t)N * 8 * 4);
  int* row_ptr = (int*)alloc((size_t)(N + 1) * 4);
  int* cursor  = (int*)alloc((size_t)N * 4);
  int* deg     = (int*)alloc((size_t)N * 4);
  int* srcs    = (int*)alloc((size_t)ET * 4);
  int* bsum    = (int*)alloc((size_t)NB * 4);
  int* boff    = (int*)alloc((size_t)NB * 4);
  (void)ws_size; (void)n_in; (void)out_size;

  dim3 b256(256);
  // CSR build (once; reused across all 5 layers)
  k_deg_init<<<NB, b256, 0, stream>>>(deg, N);
  k_count<<<(E + 255) / 256, b256, 0, stream>>>(ei, E, deg);
  k_bsum<<<NB, b256, 0, stream>>>(deg, bsum, N);
  k_bscan<<<1, b256, 0, stream>>>(bsum, boff, NB);
  k_rowptr<<<NB, b256, 0, stream>>>(deg, boff, row_ptr, cursor, N);
  k_fill<<<(ET + 255) / 256, b256, 0, stream>>>(ei, E, N, cursor, srcs);

  int gemm_grid = (N + 63) / 64;
  const float* xin = x;
  float* bufs[2] = { xA, xB };
  for (int l = 0; l < 5; l++) {
    float* xout = bufs[l & 1];
    k_gemm<<<gemm_grid, b256, 0, stream>>>(xin, Wl[l], nullptr, h, N, 0);
    if (l < 4) {
      k_al8<<<(N * 8 + 255) / 256, b256, 0, stream>>>(h, as[l], ad[l], als, ald, N);
      k_agg<8><<<(N + 3) / 4, b256, 0, stream>>>(row_ptr, srcs, als, ald, h, bl[l], xout, N);
    } else {
      k_al1<<<(N * 16 + 255) / 256, b256, 0, stream>>>(h, as[l], ad[l], als, ald, N);
      k_agg<1><<<(N + 3) / 4, b256, 0, stream>>>(row_ptr, srcs, als, ald, h, bl[l], xout, N);
    }
    xin = xout;
  }
  k_gemm<<<gemm_grid, b256, 0, stream>>>(xin, W_lin, b_lin, (float*)d_out, N, 1);
}